// Round 8
// baseline (946.577 us; speedup 1.0000x reference)
//
#include <hip/hip_runtime.h>

#define T       512
#define DIN     32
#define HCELLS  64
#define NB      16      // batch elems per block (MFMA N dim)
#define TB      1024    // 16 waves: A = waves 0-7 (layer 0), B = waves 8-15 (layer 1)
                        // within a group: wl = wid&3 (j-tile), dup = (wid>>2)&1 (activation half)
#define GRID    64      // 1024 / NB

typedef _Float16 half8  __attribute__((ext_vector_type(8)));
typedef _Float16 half2v __attribute__((ext_vector_type(2)));
typedef float    float4v __attribute__((ext_vector_type(4)));

// LDS fp16 buffers (hi only; single-fp16 weights — r7-validated precision budget)
#define STRX    40      // x rows: 32 + 8 pad
#define STRH    72      // h rows: 64 + 8 pad
#define XH_OFF  0                       // [2][16][STRX]
#define H0H_OFF (2*16*STRX)             // [2][16][STRH]
#define H1H_OFF (H0H_OFF + 2*16*STRH)
#define SB_HALFS (H1H_OFF + 2*16*STRH)

#define LOG2E   1.44269504f
#define SLOG2E  2.88539008f     // 2*log2(e); cell state kept as cs = SLOG2E * c

__device__ __forceinline__ int xidx(int p, int n, int k) { return (p * 16 + n) * STRX + k; }
__device__ __forceinline__ int hidx(int p, int n, int k) { return (p * 16 + n) * STRH + k; }

__device__ __forceinline__ void cvt8(const float* v, half8& hi) {
    #pragma unroll
    for (int e = 0; e < 8; ++e) hi[e] = (_Float16)v[e];
}

// Scaled-domain LSTM cell update on TWO elements (rows r0, r0+1 of the acc fragment):
//   acc[0]=-log2e*zi, acc[1]=-log2e*zf, acc[2]=2log2e*zg, acc[3]=-log2e*zo ; cs = 2log2e*c
__device__ __forceinline__ void cell_update2(const float4v acc[4], int r0, float* cs,
                                             half2v& hh, float* hout)
{
    #pragma unroll
    for (int e = 0; e < 2; ++e) {
        const int r = r0 + e;
        float ei = __builtin_amdgcn_exp2f(acc[0][r]);   // e^{-zi}
        float ef = __builtin_amdgcn_exp2f(acc[1][r]);   // e^{-zf}
        float G2 = __builtin_amdgcn_exp2f(acc[2][r]);   // e^{2 zg}
        float I  = 1.0f + ei, F = 1.0f + ef;
        float Gp = 1.0f + G2;
        float Gms = fmaf(SLOG2E, G2, -SLOG2E);          // s*(G2-1)
        float P   = I * Gp;
        float num = fmaf(F, Gms, cs[e] * P);
        float csn = num * __builtin_amdgcn_rcpf(F * P);
        csn = fminf(fmaxf(csn, -50.0f), 50.0f);
        cs[e] = csn;
        float eo = __builtin_amdgcn_exp2f(acc[3][r]);   // e^{-zo}
        float C2 = __builtin_amdgcn_exp2f(csn);         // e^{2 c'}
        float O  = 1.0f + eo;
        float Cp = 1.0f + C2, Cm = C2 - 1.0f;
        float h  = Cm * __builtin_amdgcn_rcpf(O * Cp);
        if (hout) hout[e] = h;
        hh[e] = (_Float16)h;
    }
}

__global__ void __launch_bounds__(TB, 4)
lstm2_mfma_kernel(const float* __restrict__ x,
                  const float* __restrict__ Wih0, const float* __restrict__ Whh0,
                  const float* __restrict__ bih0, const float* __restrict__ bhh0,
                  const float* __restrict__ Wih1, const float* __restrict__ Whh1,
                  const float* __restrict__ bih1, const float* __restrict__ bhh1,
                  const float* __restrict__ W1,   const float* __restrict__ b1,
                  const float* __restrict__ W2,   const float* __restrict__ b2,
                  float* __restrict__ out)
{
    const int tid  = threadIdx.x;
    const int wid  = tid >> 6;          // 0..15
    const int grp  = wid >> 3;          // 0 = layer-0 group, 1 = layer-1 group
    const int wl   = wid & 3;           // j-tile within group
    const int dup  = (wid >> 2) & 1;    // duplicate-MFMA pair: which activation half
    const int lane = tid & 63;
    const int n16  = lane & 15;         // MFMA free index / local batch
    const int q    = lane >> 4;         // quad 0..3
    const int j0   = wl * 16 + q * 4;   // fragment's hidden-unit base (4 rows)
    const int jr   = j0 + 2 * dup;      // this wave's 2 activation rows
    const int b0   = blockIdx.x * NB;

    __shared__ __align__(16) _Float16 SB[SB_HALFS];
    __shared__ __align__(16) float HS[16 * 68 + 16 * 33];

    const float gsc[4] = {-LOG2E, -LOG2E, SLOG2E, -LOG2E};

    // ---------------- per-group weight fragments (single fp16); dup waves load identical ----------------
    half8 ah[4][4];
    float4v biasv[4];

    #pragma unroll
    for (int l = 0; l < 4; ++l) {
        const int row = (l * 4 + wl) * 16 + n16;
        const float g = gsc[l];
        float v[8];
        if (grp == 0) {
            {
                const float4* p = (const float4*)(Wih0 + row * DIN + q * 8);
                float4 u0 = p[0], u1 = p[1];
                v[0]=g*u0.x; v[1]=g*u0.y; v[2]=g*u0.z; v[3]=g*u0.w;
                v[4]=g*u1.x; v[5]=g*u1.y; v[6]=g*u1.z; v[7]=g*u1.w;
                cvt8(v, ah[l][0]);
            }
            #pragma unroll
            for (int kt = 1; kt < 3; ++kt) {
                const float4* p = (const float4*)(Whh0 + row * HCELLS + (kt - 1) * 32 + q * 8);
                float4 u0 = p[0], u1 = p[1];
                v[0]=g*u0.x; v[1]=g*u0.y; v[2]=g*u0.z; v[3]=g*u0.w;
                v[4]=g*u1.x; v[5]=g*u1.y; v[6]=g*u1.z; v[7]=g*u1.w;
                cvt8(v, ah[l][kt]);
            }
            const int r0 = l * 64 + j0;
            float4v bi = *(const float4v*)(bih0 + r0);
            float4v bh = *(const float4v*)(bhh0 + r0);
            biasv[l] = (bi + bh) * g;
        } else {
            #pragma unroll
            for (int kt = 0; kt < 4; ++kt) {
                const float* base = (kt < 2) ? (Wih1 + row * HCELLS + kt * 32)
                                             : (Whh1 + row * HCELLS + (kt - 2) * 32);
                const float4* p = (const float4*)(base + q * 8);
                float4 u0 = p[0], u1 = p[1];
                v[0]=g*u0.x; v[1]=g*u0.y; v[2]=g*u0.z; v[3]=g*u0.w;
                v[4]=g*u1.x; v[5]=g*u1.y; v[6]=g*u1.z; v[7]=g*u1.w;
                cvt8(v, ah[l][kt]);
            }
            const int r0 = l * 64 + j0;
            float4v bi = *(const float4v*)(bih1 + r0);
            float4v bh = *(const float4v*)(bhh1 + r0);
            biasv[l] = (bi + bh) * g;
        }
    }

    // ---------------- zero LDS, stage x(0) -> slot 0 ----------------
    for (int i = tid; i < SB_HALFS / 2; i += TB) ((int*)SB)[i] = 0;

    const bool isldr = (tid < 256);     // x-loader role: waves 0-3 only
    const int nx = (tid >> 4) & 15;     // loader batch 0..15
    const int kp = (tid & 15) * 2;      // loader k pair 0..30
    const float* xp0 = isldr ? (x + (size_t)(b0 + nx) * T * DIN + kp) : nullptr;
    __syncthreads();
    if (isldr) {
        float2 xv = *(const float2*)xp0;
        half2v hi = {(_Float16)xv.x, (_Float16)xv.y};
        *(half2v*)&SB[XH_OFF + xidx(0, nx, kp)] = hi;
    }
    __syncthreads();

    float cs[2] = {0, 0};
    float hlast[2];
    const float* xp = isldr ? (xp0 + DIN) : nullptr;

    // ---------------- pipelined time loop: ONE barrier per region ----------------
    // region t: A computes L0(t); B computes L1(t-1) (t>=1); v(tau) lives in slot (tau+1)&1
    #pragma unroll 2
    for (int t = 0; t < T; ++t) {
        const int pr = t & 1, pw = pr ^ 1;

        if (grp == 0) {
            // prefetch x(t+1)
            float2 xv;
            const bool havex = isldr && (t + 1 < T);
            if (havex) xv = *(const float2*)xp;
            if (isldr) xp += DIN;

            float4v acc[4];
            #pragma unroll
            for (int l = 0; l < 4; ++l) acc[l] = biasv[l];
            // kt=0: x(t) @ X[pr]
            {
                half8 bh = *(const half8*)&SB[XH_OFF + xidx(pr, n16, q * 8)];
                #pragma unroll
                for (int l = 0; l < 4; ++l)
                    acc[l] = __builtin_amdgcn_mfma_f32_16x16x32_f16(ah[l][0], bh, acc[l], 0, 0, 0);
            }
            // kt=1,2: h0(t-1) @ H0[pr]
            #pragma unroll
            for (int kt = 1; kt < 3; ++kt) {
                half8 bh = *(const half8*)&SB[H0H_OFF + hidx(pr, n16, (kt - 1) * 32 + q * 8)];
                #pragma unroll
                for (int l = 0; l < 4; ++l)
                    acc[l] = __builtin_amdgcn_mfma_f32_16x16x32_f16(ah[l][kt], bh, acc[l], 0, 0, 0);
            }
            half2v hh;
            cell_update2(acc, 2 * dup, cs, hh, nullptr);
            *(half2v*)&SB[H0H_OFF + hidx(pw, n16, jr)] = hh;   // h0(t) rows jr,jr+1 -> slot pw
            // stage x(t+1) -> X[pw]
            if (havex) {
                half2v hi = {(_Float16)xv.x, (_Float16)xv.y};
                *(half2v*)&SB[XH_OFF + xidx(pw, nx, kp)] = hi;
            }
        } else if (t > 0) {
            // L1(t-1): h0(t-1) @ H0[pr], h1(t-2) @ H1[pw]
            float4v acc[4];
            #pragma unroll
            for (int l = 0; l < 4; ++l) acc[l] = biasv[l];
            #pragma unroll
            for (int kt = 0; kt < 4; ++kt) {
                half8 bh = (kt < 2)
                    ? *(const half8*)&SB[H0H_OFF + hidx(pr, n16, kt * 32 + q * 8)]
                    : *(const half8*)&SB[H1H_OFF + hidx(pw, n16, (kt - 2) * 32 + q * 8)];
                #pragma unroll
                for (int l = 0; l < 4; ++l)
                    acc[l] = __builtin_amdgcn_mfma_f32_16x16x32_f16(ah[l][kt], bh, acc[l], 0, 0, 0);
            }
            half2v hh;
            cell_update2(acc, 2 * dup, cs, hh, nullptr);
            *(half2v*)&SB[H1H_OFF + hidx(pr, n16, jr)] = hh;   // h1(t-1) rows jr,jr+1 -> slot pr
        }
        __syncthreads();
    }

    // ---------------- epilogue: B computes L1(T-1) ----------------
    // h0(T-1) in slot 0 ; h1(T-2) in slot 1   (T even)
    float* h1f = HS;             // [16][68]
    float* hid = HS + 16 * 68;   // [16][33]
    if (grp == 1) {
        float4v acc[4];
        #pragma unroll
        for (int l = 0; l < 4; ++l) acc[l] = biasv[l];
        #pragma unroll
        for (int kt = 0; kt < 4; ++kt) {
            half8 bh = (kt < 2)
                ? *(const half8*)&SB[H0H_OFF + hidx(0, n16, kt * 32 + q * 8)]
                : *(const half8*)&SB[H1H_OFF + hidx(1, n16, (kt - 2) * 32 + q * 8)];
            #pragma unroll
            for (int l = 0; l < 4; ++l)
                acc[l] = __builtin_amdgcn_mfma_f32_16x16x32_f16(ah[l][kt], bh, acc[l], 0, 0, 0);
        }
        half2v hh;
        cell_update2(acc, 2 * dup, cs, hh, hlast);
        *(float2*)&h1f[n16 * 68 + jr] = *(const float2*)hlast;
    }
    __syncthreads();

    // ---------------- head: relu(h1 @ W1^T + b1) @ W2^T + b2 ----------------
    if (tid < 256) {
        const int n2 = tid >> 4, m = tid & 15;
        float s0 = b1[m], s1 = b1[m + 16];
        const float* w0p = W1 + m * HCELLS;
        const float* w1p = W1 + (m + 16) * HCELLS;
        #pragma unroll
        for (int j = 0; j < HCELLS; ++j) {
            float hv = h1f[n2 * 68 + j];
            s0 = fmaf(w0p[j], hv, s0);
            s1 = fmaf(w1p[j], hv, s1);
        }
        hid[n2 * 33 + m]      = fmaxf(s0, 0.0f);
        hid[n2 * 33 + m + 16] = fmaxf(s1, 0.0f);
    }
    __syncthreads();

    if (tid < NB) {
        float s = b2[0];
        #pragma unroll
        for (int m = 0; m < 32; ++m) s = fmaf(W2[m], hid[tid * 33 + m], s);
        out[b0 + tid] = s;
    }
}

extern "C" void kernel_launch(void* const* d_in, const int* in_sizes, int n_in,
                              void* d_out, int out_size, void* d_ws, size_t ws_size,
                              hipStream_t stream) {
    const float* x    = (const float*)d_in[0];
    const float* Wih0 = (const float*)d_in[1];
    const float* Whh0 = (const float*)d_in[2];
    const float* bih0 = (const float*)d_in[3];
    const float* bhh0 = (const float*)d_in[4];
    const float* Wih1 = (const float*)d_in[5];
    const float* Whh1 = (const float*)d_in[6];
    const float* bih1 = (const float*)d_in[7];
    const float* bhh1 = (const float*)d_in[8];
    const float* W1   = (const float*)d_in[9];
    const float* b1   = (const float*)d_in[10];
    const float* W2   = (const float*)d_in[11];
    const float* b2   = (const float*)d_in[12];
    float* out = (float*)d_out;

    hipLaunchKernelGGL(lstm2_mfma_kernel, dim3(GRID), dim3(TB), 0, stream,
                       x, Wih0, Whh0, bih0, bhh0, Wih1, Whh1, bih1, bhh1,
                       W1, b1, W2, b2, out);
}

// Round 9
// 592.787 us; speedup vs baseline: 1.5968x; 1.5968x over previous
//
#include <hip/hip_runtime.h>

#define T       512
#define DIN     32
#define HCELLS  64
#define NB      16      // batch elems per block (MFMA N dim)
#define TB      1024    // 16 waves: A = waves 0-7 (layer 0), B = waves 8-15 (layer 1)
                        // within a group: wl = wid&3 (j-tile), dup = (wid>>2)&1 (activation half)
#define GRID    64      // 1024 / NB

typedef _Float16 half8  __attribute__((ext_vector_type(8)));
typedef _Float16 half2v __attribute__((ext_vector_type(2)));
typedef float    float4v __attribute__((ext_vector_type(4)));

// LDS fp16 buffers (hi only; single-fp16 weights — r7-validated precision budget)
#define STRX    40      // x rows: 32 + 8 pad
#define STRH    72      // h rows: 64 + 8 pad
#define XH_OFF  0                       // [2][16][STRX]
#define H0H_OFF (2*16*STRX)             // [2][16][STRH]
#define H1H_OFF (H0H_OFF + 2*16*STRH)
#define SB_HALFS (H1H_OFF + 2*16*STRH)

#define LOG2E   1.44269504f
#define SLOG2E  2.88539008f     // 2*log2(e); cell state kept as cs = SLOG2E * c

__device__ __forceinline__ int xidx(int p, int n, int k) { return (p * 16 + n) * STRX + k; }
__device__ __forceinline__ int hidx(int p, int n, int k) { return (p * 16 + n) * STRH + k; }

__device__ __forceinline__ void cvt8(const float* v, half8& hi) {
    #pragma unroll
    for (int e = 0; e < 8; ++e) hi[e] = (_Float16)v[e];
}

// Scaled-domain LSTM cell update on rows R0, R0+1 of the acc fragment.
// R0 is a TEMPLATE parameter: all vector indices compile-time (r8's runtime
// index forced acc[] to scratch — WRITE_SIZE 4 KB -> 4.1 MB, 2.4x regression).
//   acc[0]=-log2e*zi, acc[1]=-log2e*zf, acc[2]=2log2e*zg, acc[3]=-log2e*zo ; cs = 2log2e*c
template<int R0>
__device__ __forceinline__ void cell_update2(const float4v acc[4], float* cs,
                                             half2v& hh, float* hout)
{
    #pragma unroll
    for (int e = 0; e < 2; ++e) {
        constexpr int roff = R0;  // compile-time
        float ei = __builtin_amdgcn_exp2f(acc[0][roff + e]);   // e^{-zi}
        float ef = __builtin_amdgcn_exp2f(acc[1][roff + e]);   // e^{-zf}
        float G2 = __builtin_amdgcn_exp2f(acc[2][roff + e]);   // e^{2 zg}
        float I  = 1.0f + ei, F = 1.0f + ef;
        float Gp = 1.0f + G2;
        float Gms = fmaf(SLOG2E, G2, -SLOG2E);          // s*(G2-1)
        float P   = I * Gp;
        float num = fmaf(F, Gms, cs[e] * P);
        float csn = num * __builtin_amdgcn_rcpf(F * P);
        csn = fminf(fmaxf(csn, -50.0f), 50.0f);
        cs[e] = csn;
        float eo = __builtin_amdgcn_exp2f(acc[3][roff + e]);   // e^{-zo}
        float C2 = __builtin_amdgcn_exp2f(csn);                // e^{2 c'}
        float O  = 1.0f + eo;
        float Cp = 1.0f + C2, Cm = C2 - 1.0f;
        float h  = Cm * __builtin_amdgcn_rcpf(O * Cp);
        if (hout) hout[e] = h;
        hh[e] = (_Float16)h;
    }
}

__global__ void __launch_bounds__(TB, 4)
lstm2_mfma_kernel(const float* __restrict__ x,
                  const float* __restrict__ Wih0, const float* __restrict__ Whh0,
                  const float* __restrict__ bih0, const float* __restrict__ bhh0,
                  const float* __restrict__ Wih1, const float* __restrict__ Whh1,
                  const float* __restrict__ bih1, const float* __restrict__ bhh1,
                  const float* __restrict__ W1,   const float* __restrict__ b1,
                  const float* __restrict__ W2,   const float* __restrict__ b2,
                  float* __restrict__ out)
{
    const int tid  = threadIdx.x;
    const int wid  = tid >> 6;          // 0..15
    const int grp  = wid >> 3;          // 0 = layer-0 group, 1 = layer-1 group
    const int wl   = wid & 3;           // j-tile within group
    const int dup  = (wid >> 2) & 1;    // duplicate-MFMA pair: which activation half
    const int lane = tid & 63;
    const int n16  = lane & 15;         // MFMA free index / local batch
    const int q    = lane >> 4;         // quad 0..3
    const int j0   = wl * 16 + q * 4;   // fragment's hidden-unit base (4 rows)
    const int jr   = j0 + 2 * dup;      // this wave's 2 activation rows
    const int b0   = blockIdx.x * NB;

    __shared__ __align__(16) _Float16 SB[SB_HALFS];
    __shared__ __align__(16) float HS[16 * 68 + 16 * 33];

    const float gsc[4] = {-LOG2E, -LOG2E, SLOG2E, -LOG2E};

    // ---------------- per-group weight fragments (single fp16); dup waves load identical ----------------
    half8 ah[4][4];
    float4v biasv[4];

    #pragma unroll
    for (int l = 0; l < 4; ++l) {
        const int row = (l * 4 + wl) * 16 + n16;
        const float g = gsc[l];
        float v[8];
        if (grp == 0) {
            {
                const float4* p = (const float4*)(Wih0 + row * DIN + q * 8);
                float4 u0 = p[0], u1 = p[1];
                v[0]=g*u0.x; v[1]=g*u0.y; v[2]=g*u0.z; v[3]=g*u0.w;
                v[4]=g*u1.x; v[5]=g*u1.y; v[6]=g*u1.z; v[7]=g*u1.w;
                cvt8(v, ah[l][0]);
            }
            #pragma unroll
            for (int kt = 1; kt < 3; ++kt) {
                const float4* p = (const float4*)(Whh0 + row * HCELLS + (kt - 1) * 32 + q * 8);
                float4 u0 = p[0], u1 = p[1];
                v[0]=g*u0.x; v[1]=g*u0.y; v[2]=g*u0.z; v[3]=g*u0.w;
                v[4]=g*u1.x; v[5]=g*u1.y; v[6]=g*u1.z; v[7]=g*u1.w;
                cvt8(v, ah[l][kt]);
            }
            const int r0 = l * 64 + j0;
            float4v bi = *(const float4v*)(bih0 + r0);
            float4v bh = *(const float4v*)(bhh0 + r0);
            biasv[l] = (bi + bh) * g;
        } else {
            #pragma unroll
            for (int kt = 0; kt < 4; ++kt) {
                const float* base = (kt < 2) ? (Wih1 + row * HCELLS + kt * 32)
                                             : (Whh1 + row * HCELLS + (kt - 2) * 32);
                const float4* p = (const float4*)(base + q * 8);
                float4 u0 = p[0], u1 = p[1];
                v[0]=g*u0.x; v[1]=g*u0.y; v[2]=g*u0.z; v[3]=g*u0.w;
                v[4]=g*u1.x; v[5]=g*u1.y; v[6]=g*u1.z; v[7]=g*u1.w;
                cvt8(v, ah[l][kt]);
            }
            const int r0 = l * 64 + j0;
            float4v bi = *(const float4v*)(bih1 + r0);
            float4v bh = *(const float4v*)(bhh1 + r0);
            biasv[l] = (bi + bh) * g;
        }
    }

    // ---------------- zero LDS, stage x(0) -> slot 0 ----------------
    for (int i = tid; i < SB_HALFS / 2; i += TB) ((int*)SB)[i] = 0;

    const bool isldr = (tid < 256);     // x-loader role: waves 0-3 only
    const int nx = (tid >> 4) & 15;     // loader batch 0..15
    const int kp = (tid & 15) * 2;      // loader k pair 0..30
    const float* xp0 = isldr ? (x + (size_t)(b0 + nx) * T * DIN + kp) : nullptr;
    __syncthreads();
    if (isldr) {
        float2 xv = *(const float2*)xp0;
        half2v hi = {(_Float16)xv.x, (_Float16)xv.y};
        *(half2v*)&SB[XH_OFF + xidx(0, nx, kp)] = hi;
    }
    __syncthreads();

    float cs[2] = {0, 0};
    float hlast[2];
    const float* xp = isldr ? (xp0 + DIN) : nullptr;

    // ---------------- pipelined time loop: ONE barrier per region ----------------
    // region t: A computes L0(t); B computes L1(t-1) (t>=1); v(tau) lives in slot (tau+1)&1
    #pragma unroll 2
    for (int t = 0; t < T; ++t) {
        const int pr = t & 1, pw = pr ^ 1;

        if (grp == 0) {
            // prefetch x(t+1)
            float2 xv;
            const bool havex = isldr && (t + 1 < T);
            if (havex) xv = *(const float2*)xp;
            if (isldr) xp += DIN;

            float4v acc[4];
            #pragma unroll
            for (int l = 0; l < 4; ++l) acc[l] = biasv[l];
            // kt=0: x(t) @ X[pr]
            {
                half8 bh = *(const half8*)&SB[XH_OFF + xidx(pr, n16, q * 8)];
                #pragma unroll
                for (int l = 0; l < 4; ++l)
                    acc[l] = __builtin_amdgcn_mfma_f32_16x16x32_f16(ah[l][0], bh, acc[l], 0, 0, 0);
            }
            // kt=1,2: h0(t-1) @ H0[pr]
            #pragma unroll
            for (int kt = 1; kt < 3; ++kt) {
                half8 bh = *(const half8*)&SB[H0H_OFF + hidx(pr, n16, (kt - 1) * 32 + q * 8)];
                #pragma unroll
                for (int l = 0; l < 4; ++l)
                    acc[l] = __builtin_amdgcn_mfma_f32_16x16x32_f16(ah[l][kt], bh, acc[l], 0, 0, 0);
            }
            half2v hh;
            if (dup == 0) cell_update2<0>(acc, cs, hh, nullptr);
            else          cell_update2<2>(acc, cs, hh, nullptr);
            *(half2v*)&SB[H0H_OFF + hidx(pw, n16, jr)] = hh;   // h0(t) rows jr,jr+1 -> slot pw
            // stage x(t+1) -> X[pw]
            if (havex) {
                half2v hi = {(_Float16)xv.x, (_Float16)xv.y};
                *(half2v*)&SB[XH_OFF + xidx(pw, nx, kp)] = hi;
            }
        } else if (t > 0) {
            // L1(t-1): h0(t-1) @ H0[pr], h1(t-2) @ H1[pw]
            float4v acc[4];
            #pragma unroll
            for (int l = 0; l < 4; ++l) acc[l] = biasv[l];
            #pragma unroll
            for (int kt = 0; kt < 4; ++kt) {
                half8 bh = (kt < 2)
                    ? *(const half8*)&SB[H0H_OFF + hidx(pr, n16, kt * 32 + q * 8)]
                    : *(const half8*)&SB[H1H_OFF + hidx(pw, n16, (kt - 2) * 32 + q * 8)];
                #pragma unroll
                for (int l = 0; l < 4; ++l)
                    acc[l] = __builtin_amdgcn_mfma_f32_16x16x32_f16(ah[l][kt], bh, acc[l], 0, 0, 0);
            }
            half2v hh;
            if (dup == 0) cell_update2<0>(acc, cs, hh, nullptr);
            else          cell_update2<2>(acc, cs, hh, nullptr);
            *(half2v*)&SB[H1H_OFF + hidx(pr, n16, jr)] = hh;   // h1(t-1) rows jr,jr+1 -> slot pr
        }
        __syncthreads();
    }

    // ---------------- epilogue: B computes L1(T-1) ----------------
    // h0(T-1) in slot 0 ; h1(T-2) in slot 1   (T even)
    float* h1f = HS;             // [16][68]
    float* hid = HS + 16 * 68;   // [16][33]
    if (grp == 1) {
        float4v acc[4];
        #pragma unroll
        for (int l = 0; l < 4; ++l) acc[l] = biasv[l];
        #pragma unroll
        for (int kt = 0; kt < 4; ++kt) {
            half8 bh = (kt < 2)
                ? *(const half8*)&SB[H0H_OFF + hidx(0, n16, kt * 32 + q * 8)]
                : *(const half8*)&SB[H1H_OFF + hidx(1, n16, (kt - 2) * 32 + q * 8)];
            #pragma unroll
            for (int l = 0; l < 4; ++l)
                acc[l] = __builtin_amdgcn_mfma_f32_16x16x32_f16(ah[l][kt], bh, acc[l], 0, 0, 0);
        }
        half2v hh;
        if (dup == 0) cell_update2<0>(acc, cs, hh, hlast);
        else          cell_update2<2>(acc, cs, hh, hlast);
        *(float2*)&h1f[n16 * 68 + jr] = *(const float2*)hlast;
    }
    __syncthreads();

    // ---------------- head: relu(h1 @ W1^T + b1) @ W2^T + b2 ----------------
    if (tid < 256) {
        const int n2 = tid >> 4, m = tid & 15;
        float s0 = b1[m], s1 = b1[m + 16];
        const float* w0p = W1 + m * HCELLS;
        const float* w1p = W1 + (m + 16) * HCELLS;
        #pragma unroll
        for (int j = 0; j < HCELLS; ++j) {
            float hv = h1f[n2 * 68 + j];
            s0 = fmaf(w0p[j], hv, s0);
            s1 = fmaf(w1p[j], hv, s1);
        }
        hid[n2 * 33 + m]      = fmaxf(s0, 0.0f);
        hid[n2 * 33 + m + 16] = fmaxf(s1, 0.0f);
    }
    __syncthreads();

    if (tid < NB) {
        float s = b2[0];
        #pragma unroll
        for (int m = 0; m < 32; ++m) s = fmaf(W2[m], hid[tid * 33 + m], s);
        out[b0 + tid] = s;
    }
}

extern "C" void kernel_launch(void* const* d_in, const int* in_sizes, int n_in,
                              void* d_out, int out_size, void* d_ws, size_t ws_size,
                              hipStream_t stream) {
    const float* x    = (const float*)d_in[0];
    const float* Wih0 = (const float*)d_in[1];
    const float* Whh0 = (const float*)d_in[2];
    const float* bih0 = (const float*)d_in[3];
    const float* bhh0 = (const float*)d_in[4];
    const float* Wih1 = (const float*)d_in[5];
    const float* Whh1 = (const float*)d_in[6];
    const float* bih1 = (const float*)d_in[7];
    const float* bhh1 = (const float*)d_in[8];
    const float* W1   = (const float*)d_in[9];
    const float* b1   = (const float*)d_in[10];
    const float* W2   = (const float*)d_in[11];
    const float* b2   = (const float*)d_in[12];
    float* out = (float*)d_out;

    hipLaunchKernelGGL(lstm2_mfma_kernel, dim3(GRID), dim3(TB), 0, stream,
                       x, Wih0, Whh0, bih0, bhh0, Wih1, Whh1, bih1, bhh1,
                       W1, b1, W2, b2, out);
}

// Round 10
// 461.633 us; speedup vs baseline: 2.0505x; 1.2841x over previous
//
#include <hip/hip_runtime.h>

#define T       512
#define DIN     32
#define HCELLS  64
#define NB      16      // batch elems per block (MFMA N dim)
#define TB      512     // 8 waves: group A = waves 0-3 (layer 0), group B = waves 4-7 (layer 1)
#define GRID    64      // 1024 / NB

typedef _Float16 half8  __attribute__((ext_vector_type(8)));
typedef _Float16 half4v __attribute__((ext_vector_type(4)));
typedef float    float4v __attribute__((ext_vector_type(4)));

// LDS fp16 buffers: h0/h1 only — x bypasses LDS entirely (r10: direct global
// reads; each A-thread's x fragment is 8 contiguous floats, VMEM pipe idle).
#define STRH    72      // h rows: 64 + 8 pad
#define H0H_OFF 0                       // [2][16][STRH]
#define H1H_OFF (2*16*STRH)
#define SB_HALFS (H1H_OFF + 2*16*STRH)

#define LOG2E   1.44269504f
#define SLOG2E  2.88539008f     // 2*log2(e); cell state kept as cs = SLOG2E * c

__device__ __forceinline__ int hidx(int p, int n, int k) { return (p * 16 + n) * STRH + k; }

__device__ __forceinline__ void cvt8(const float* v, half8& hi) {
    #pragma unroll
    for (int e = 0; e < 8; ++e) hi[e] = (_Float16)v[e];
}

// Scaled-domain LSTM cell update (gate scales folded into weights):
//   acc[0]=-log2e*zi, acc[1]=-log2e*zf, acc[2]=2log2e*zg, acc[3]=-log2e*zo ; cs = 2log2e*c
__device__ __forceinline__ void cell_update(const float4v acc[4], float* cs,
                                            half4v& hh, float* hout)
{
    #pragma unroll
    for (int r = 0; r < 4; ++r) {
        float ei = __builtin_amdgcn_exp2f(acc[0][r]);   // e^{-zi}
        float ef = __builtin_amdgcn_exp2f(acc[1][r]);   // e^{-zf}
        float G2 = __builtin_amdgcn_exp2f(acc[2][r]);   // e^{2 zg}
        float I  = 1.0f + ei, F = 1.0f + ef;
        float Gp = 1.0f + G2;
        float Gms = fmaf(SLOG2E, G2, -SLOG2E);          // s*(G2-1)
        float P   = I * Gp;
        float num = fmaf(F, Gms, cs[r] * P);
        float csn = num * __builtin_amdgcn_rcpf(F * P);
        csn = fminf(fmaxf(csn, -50.0f), 50.0f);
        cs[r] = csn;
        float eo = __builtin_amdgcn_exp2f(acc[3][r]);   // e^{-zo}
        float C2 = __builtin_amdgcn_exp2f(csn);         // e^{2 c'}
        float O  = 1.0f + eo;
        float Cp = 1.0f + C2, Cm = C2 - 1.0f;
        float h  = Cm * __builtin_amdgcn_rcpf(O * Cp);
        if (hout) hout[r] = h;
        hh[r] = (_Float16)h;
    }
}

__global__ void __launch_bounds__(TB, 2)
lstm2_mfma_kernel(const float* __restrict__ x,
                  const float* __restrict__ Wih0, const float* __restrict__ Whh0,
                  const float* __restrict__ bih0, const float* __restrict__ bhh0,
                  const float* __restrict__ Wih1, const float* __restrict__ Whh1,
                  const float* __restrict__ bih1, const float* __restrict__ bhh1,
                  const float* __restrict__ W1,   const float* __restrict__ b1,
                  const float* __restrict__ W2,   const float* __restrict__ b2,
                  float* __restrict__ out)
{
    const int tid  = threadIdx.x;
    const int wid  = tid >> 6;
    const int grp  = wid >> 2;          // 0 = layer-0 group, 1 = layer-1 group
    const int wl   = wid & 3;           // local wave in group
    const int lane = tid & 63;
    const int n16  = lane & 15;         // MFMA free index / local batch
    const int q    = lane >> 4;         // quad 0..3
    const int j0   = wl * 16 + q * 4;   // this thread's hidden-unit base (4 rows)
    const int b0   = blockIdx.x * NB;

    __shared__ __align__(16) _Float16 SB[SB_HALFS];
    __shared__ __align__(16) float HS[16 * 68 + 16 * 33];

    const float gsc[4] = {-LOG2E, -LOG2E, SLOG2E, -LOG2E};

    // ---------------- per-group weight fragments (single fp16) ----------------
    half8 ah[4][4];
    float4v biasv[4];

    #pragma unroll
    for (int l = 0; l < 4; ++l) {
        const int row = (l * 4 + wl) * 16 + n16;
        const float g = gsc[l];
        float v[8];
        if (grp == 0) {
            {
                const float4* p = (const float4*)(Wih0 + row * DIN + q * 8);
                float4 u0 = p[0], u1 = p[1];
                v[0]=g*u0.x; v[1]=g*u0.y; v[2]=g*u0.z; v[3]=g*u0.w;
                v[4]=g*u1.x; v[5]=g*u1.y; v[6]=g*u1.z; v[7]=g*u1.w;
                cvt8(v, ah[l][0]);
            }
            #pragma unroll
            for (int kt = 1; kt < 3; ++kt) {
                const float4* p = (const float4*)(Whh0 + row * HCELLS + (kt - 1) * 32 + q * 8);
                float4 u0 = p[0], u1 = p[1];
                v[0]=g*u0.x; v[1]=g*u0.y; v[2]=g*u0.z; v[3]=g*u0.w;
                v[4]=g*u1.x; v[5]=g*u1.y; v[6]=g*u1.z; v[7]=g*u1.w;
                cvt8(v, ah[l][kt]);
            }
            const int r0 = l * 64 + j0;
            float4v bi = *(const float4v*)(bih0 + r0);
            float4v bh = *(const float4v*)(bhh0 + r0);
            biasv[l] = (bi + bh) * g;
        } else {
            #pragma unroll
            for (int kt = 0; kt < 4; ++kt) {
                const float* base = (kt < 2) ? (Wih1 + row * HCELLS + kt * 32)
                                             : (Whh1 + row * HCELLS + (kt - 2) * 32);
                const float4* p = (const float4*)(base + q * 8);
                float4 u0 = p[0], u1 = p[1];
                v[0]=g*u0.x; v[1]=g*u0.y; v[2]=g*u0.z; v[3]=g*u0.w;
                v[4]=g*u1.x; v[5]=g*u1.y; v[6]=g*u1.z; v[7]=g*u1.w;
                cvt8(v, ah[l][kt]);
            }
            const int r0 = l * 64 + j0;
            float4v bi = *(const float4v*)(bih1 + r0);
            float4v bh = *(const float4v*)(bhh1 + r0);
            biasv[l] = (bi + bh) * g;
        }
    }

    // ---------------- zero LDS (h buffers read at t=0,1 before written) ----------------
    for (int i = tid; i < SB_HALFS / 2; i += TB) ((int*)SB)[i] = 0;

    // A-thread x pointer: fragment = 8 contiguous floats at [b0+n16][t][q*8]
    const float* xbase = x + ((size_t)(b0 + n16) * T) * DIN + q * 8;
    float4 xa, xb;        // x(t) fragment (fp32, in regs)
    float4 xa2, xb2;      // prefetched x(t+1)
    if (grp == 0) {
        xa = *(const float4*)(xbase);
        xb = *(const float4*)(xbase + 4);
    }
    const float* xp = xbase + DIN;   // points at x(t+1)
    __syncthreads();

    float cs[4] = {0, 0, 0, 0};
    float hlast[4];

    // ---------------- pipelined time loop: ONE barrier per region ----------------
    // region t: A computes L0(t); B computes L1(t-1) (t>=1); v(tau) lives in slot (tau+1)&1
    #pragma unroll 2
    for (int t = 0; t < T; ++t) {
        const int pr = t & 1, pw = pr ^ 1;

        if (grp == 0) {
            // prefetch x(t+1) into regs (region >> HBM latency; consumed next region)
            const bool havex = (t + 1 < T);
            if (havex) {
                xa2 = *(const float4*)(xp);
                xb2 = *(const float4*)(xp + 4);
            }
            xp += DIN;

            float4v acc[4];
            #pragma unroll
            for (int l = 0; l < 4; ++l) acc[l] = biasv[l];
            // kt=0: x(t) from registers — issues immediately post-barrier, no LDS wait
            {
                float xf[8] = {xa.x, xa.y, xa.z, xa.w, xb.x, xb.y, xb.z, xb.w};
                half8 bx;
                cvt8(xf, bx);
                #pragma unroll
                for (int l = 0; l < 4; ++l)
                    acc[l] = __builtin_amdgcn_mfma_f32_16x16x32_f16(ah[l][0], bx, acc[l], 0, 0, 0);
            }
            // kt=1,2: h0(t-1) @ H0[pr]
            #pragma unroll
            for (int kt = 1; kt < 3; ++kt) {
                half8 bh = *(const half8*)&SB[H0H_OFF + hidx(pr, n16, (kt - 1) * 32 + q * 8)];
                #pragma unroll
                for (int l = 0; l < 4; ++l)
                    acc[l] = __builtin_amdgcn_mfma_f32_16x16x32_f16(ah[l][kt], bh, acc[l], 0, 0, 0);
            }
            half4v hh;
            cell_update(acc, cs, hh, nullptr);
            *(half4v*)&SB[H0H_OFF + hidx(pw, n16, j0)] = hh;   // h0(t) -> slot pw
            // rotate x prefetch
            if (havex) { xa = xa2; xb = xb2; }
        } else if (t > 0) {
            // L1(t-1): h0(t-1) @ H0[pr], h1(t-2) @ H1[pw]
            float4v acc[4];
            #pragma unroll
            for (int l = 0; l < 4; ++l) acc[l] = biasv[l];
            #pragma unroll
            for (int kt = 0; kt < 4; ++kt) {
                half8 bh = (kt < 2)
                    ? *(const half8*)&SB[H0H_OFF + hidx(pr, n16, kt * 32 + q * 8)]
                    : *(const half8*)&SB[H1H_OFF + hidx(pw, n16, (kt - 2) * 32 + q * 8)];
                #pragma unroll
                for (int l = 0; l < 4; ++l)
                    acc[l] = __builtin_amdgcn_mfma_f32_16x16x32_f16(ah[l][kt], bh, acc[l], 0, 0, 0);
            }
            half4v hh;
            cell_update(acc, cs, hh, nullptr);
            *(half4v*)&SB[H1H_OFF + hidx(pr, n16, j0)] = hh;   // h1(t-1) -> slot pr
        }
        __syncthreads();
    }

    // ---------------- epilogue: B computes L1(T-1) ----------------
    // h0(T-1) in slot 0 ; h1(T-2) in slot 1   (T even)
    float* h1f = HS;             // [16][68]
    float* hid = HS + 16 * 68;   // [16][33]
    if (grp == 1) {
        float4v acc[4];
        #pragma unroll
        for (int l = 0; l < 4; ++l) acc[l] = biasv[l];
        #pragma unroll
        for (int kt = 0; kt < 4; ++kt) {
            half8 bh = (kt < 2)
                ? *(const half8*)&SB[H0H_OFF + hidx(0, n16, kt * 32 + q * 8)]
                : *(const half8*)&SB[H1H_OFF + hidx(1, n16, (kt - 2) * 32 + q * 8)];
            #pragma unroll
            for (int l = 0; l < 4; ++l)
                acc[l] = __builtin_amdgcn_mfma_f32_16x16x32_f16(ah[l][kt], bh, acc[l], 0, 0, 0);
        }
        half4v hh;
        cell_update(acc, cs, hh, hlast);
        *(float4*)&h1f[n16 * 68 + j0] = *(const float4*)hlast;
    }
    __syncthreads();

    // ---------------- head: relu(h1 @ W1^T + b1) @ W2^T + b2 ----------------
    if (tid < 256) {
        const int n2 = tid >> 4, m = tid & 15;
        float s0 = b1[m], s1 = b1[m + 16];
        const float* w0p = W1 + m * HCELLS;
        const float* w1p = W1 + (m + 16) * HCELLS;
        #pragma unroll
        for (int j = 0; j < HCELLS; ++j) {
            float hv = h1f[n2 * 68 + j];
            s0 = fmaf(w0p[j], hv, s0);
            s1 = fmaf(w1p[j], hv, s1);
        }
        hid[n2 * 33 + m]      = fmaxf(s0, 0.0f);
        hid[n2 * 33 + m + 16] = fmaxf(s1, 0.0f);
    }
    __syncthreads();

    if (tid < NB) {
        float s = b2[0];
        #pragma unroll
        for (int m = 0; m < 32; ++m) s = fmaf(W2[m], hid[tid * 33 + m], s);
        out[b0 + tid] = s;
    }
}

extern "C" void kernel_launch(void* const* d_in, const int* in_sizes, int n_in,
                              void* d_out, int out_size, void* d_ws, size_t ws_size,
                              hipStream_t stream) {
    const float* x    = (const float*)d_in[0];
    const float* Wih0 = (const float*)d_in[1];
    const float* Whh0 = (const float*)d_in[2];
    const float* bih0 = (const float*)d_in[3];
    const float* bhh0 = (const float*)d_in[4];
    const float* Wih1 = (const float*)d_in[5];
    const float* Whh1 = (const float*)d_in[6];
    const float* bih1 = (const float*)d_in[7];
    const float* bhh1 = (const float*)d_in[8];
    const float* W1   = (const float*)d_in[9];
    const float* b1   = (const float*)d_in[10];
    const float* W2   = (const float*)d_in[11];
    const float* b2   = (const float*)d_in[12];
    float* out = (float*)d_out;

    hipLaunchKernelGGL(lstm2_mfma_kernel, dim3(GRID), dim3(TB), 0, stream,
                       x, Wih0, Whh0, bih0, bhh0, Wih1, Whh1, bih1, bhh1,
                       W1, b1, W2, b2, out);
}